// Round 8
// baseline (3621.083 us; speedup 1.0000x reference)
//
#include <hip/hip_runtime.h>
#include <hip/hip_bf16.h>

typedef unsigned short u16;
typedef unsigned int u32;
typedef unsigned long long u64;
typedef __attribute__((ext_vector_type(8))) short bf16x8;   // 8 bf16 (4 VGPRs)
typedef __attribute__((ext_vector_type(4))) float f32x4;

#define MFMA(a,b,c) __builtin_amdgcn_mfma_f32_16x16x32_bf16((a),(b),(c),0,0,0)
#define AGENT __HIP_MEMORY_SCOPE_AGENT

// v9: flag-gated single data reads + deep rings. Congestion model (v1..v8):
// every L2-freshness trick (inv/swap/beacons/plain rounds) is refuted; the
// agent/IC path is the only reliable medium, and its apparent ~3.5us
// latency was POLL CONGESTION: full 32-64KB data re-reads per round x 256
// wgs ~ 15-30 TB/s of IC traffic. Fix:
//  - producers fire tagged data stores (no ordering waits), then ONE
//    advisory flag word (tag). Consumers spin on 16 flag words (64B/round,
//    ~500x less traffic), then read data ONCE; embedded per-word tags
//    verify (retry covers flag-ahead-of-data races).
//  - h5 ring 8-deep (slot=tag&7) + GRU5 WAR guard at SLACK-7
//    (flag6 >= t-7): never binds (GRU6 lags ~1.5), decouples the chains.
//    Safety: GRU5 skew<=1 (self-sync via flag5); GRU6 readers of h5[t-8]
//    are exactly what the guard waits out. h6 ring 4-deep (slot=tag&3):
//    GRU6 peers self-synchronized to skew<=1 -> distance-safe, no guard.
//  - dropped: XCD claiming, dual stores, plain/L2 rounds, beacons, swap.
//  - kept: 40KB pad (1 wg/CU), zreg staging, msk/x2 prefetch, self-word
//    register substitution, single trailing sync.
//
// B=128, T=512, LAT=256, F2=64, H=512, DIN=320, 3H=1536
// 256 wgs: rgp = wg&7 (16 rows each), rid = wg>>3: rid<16 GRU5 slice,
//          else GRU6 slice (32 h-cols each).
// iter t (514): GRU5 consumes h5[t-1] (tag t, slot t&7), produces h5[t]
//   (tag t+1, slot (t+1)&7), t<512. GRU6 consumes h5[t-1] + h6[t-2]
//   (tag t-1, slot (t-1)&3), produces h6[t-1] (tag t, slot t&3),
//   1<=t<=512; dec[t-2] (t>=2).
// Data words: u32 = (step_tag<<16)|bf16, self-validating.
// Flags: flgX[(tag&3)*8 + rgp][32] u32 = tag, one per producer slice.

__device__ __forceinline__ u16 f2bf(float f) {
    u32 u = __float_as_uint(f);
    u32 r = (u + 0x7fffu + ((u >> 16) & 1u)) >> 16;
    return (u16)r;
}
__device__ __forceinline__ float bf2f(u16 v) { return __uint_as_float(((u32)v) << 16); }
__device__ __forceinline__ float sat01(float x) { return fminf(1.f, fmaxf(0.f, x)); }
__device__ __forceinline__ float ftanh(float x) {
    x = fminf(10.f, fmaxf(-10.f, x));
    float e = __expf(2.f * x);
    return (e - 1.f) / (e + 1.f);
}

// Spin until all 16 producer flags >= exp. 64B/round. Monotone -> uniform.
__device__ __forceinline__ void flagwait(const u32* f, u32 exp) {
    while (true) {
        u32 v = __hip_atomic_load(&f[threadIdx.x & 15], __ATOMIC_RELAXED, AGENT);
        if (__all((int)(v >= exp))) break;
        __builtin_amdgcn_s_sleep(1);
    }
}

// One tagged 16-u64 data read; self word substituted from registers;
// retries only if a tag mismatches (flag led data / transient).
__device__ __forceinline__ void readD(const u64* __restrict__ src, int cth, u32 exp,
                                      int self_k, u64 self_w, u64* v) {
    while (true) {
#pragma unroll
        for (int k = 0; k < 16; ++k) {
            u64 x = __hip_atomic_load(&src[cth + 16 * k], __ATOMIC_RELAXED, AGENT);
            v[k] = (k == self_k) ? self_w : x;
        }
        bool ok = true;
#pragma unroll
        for (int k = 0; k < 16; ++k) {
            u32 lo = (u32)v[k], hi = (u32)(v[k] >> 32);
            if (((lo >> 16) != exp) | ((hi >> 16) != exp)) ok = false;
        }
        if (ok) break;
        __builtin_amdgcn_s_sleep(1);
    }
}

__device__ __forceinline__ bf16x8 loadB(const float* __restrict__ M, int k0, int colbase,
                                        int l15, int q8) {
    const float* p = M + (size_t)(k0 + q8) * 1536 + colbase + l15;
    bf16x8 r;
#pragma unroll
    for (int j = 0; j < 8; ++j) r[j] = (short)f2bf(p[(size_t)j * 1536]);
    return r;
}

__device__ __forceinline__ bf16x8 ldsA(const u16* s, int stride, int colbase, int l15, int q8) {
    return *(const bf16x8*)(s + l15 * stride + colbase + q8);
}

__global__ void zero_ws_kernel(u32* ws) {
    int i = blockIdx.x * 256 + threadIdx.x;
    if (i < 788480) ws[i] = 0u;  // h5w[8][128][512] + h6w[4][128][512] + flg5 + flg6
}

__global__ void __launch_bounds__(256, 1)
gru_fused(const float* __restrict__ zin, const float* __restrict__ x2,
          const float* __restrict__ msk, const float* __restrict__ dmsk,
          const float* __restrict__ W5, const float* __restrict__ U5,
          const float* __restrict__ bi5, const float* __restrict__ br5,
          const float* __restrict__ W6, const float* __restrict__ U6,
          const float* __restrict__ bi6, const float* __restrict__ br6,
          const float* __restrict__ Wd, const float* __restrict__ bdp,
          float* __restrict__ out, u32* __restrict__ h5w,
          u32* __restrict__ h6w, u32* __restrict__ flg5,
          u32* __restrict__ flg6)
{
    const int wg = blockIdx.x;
    const int rgp = wg & 7;
    const int rid = wg >> 3;
    const bool is6 = rid >= 16;
    const int slice = is6 ? (rid - 16) : rid;
    const int row0 = rgp << 4;
    const int sb = slice << 5;
    const int tid = threadIdx.x;
    const int wv = tid >> 6, lane = tid & 63;
    const int l15 = lane & 15, q8 = (lane >> 4) << 3;

    __shared__ u16 stg[16 * 1032];
    __shared__ float exch[8 * 16 * 17];
    __shared__ u32 lds_pad[10240];   // 40KB: total LDS > 80KB -> 1 wg/CU forced

    ((volatile u32*)lds_pad)[tid] = 0u;   // keep pad alive

    const int ct = wv & 1;
    const int gMain = (wv < 2) ? 0 : 1;
    const int colMain = gMain * 512 + sb + ct * 16;
    const int colH = 1024 + sb + ct * 16;

    const float* bi = is6 ? bi6 : bi5;
    const float* br = is6 ? br6 : br5;
    const float biasM = bi[colMain + l15] + br[colMain + l15];
    const float biasS = (wv < 2) ? bi[colH + l15] : br[colH + l15];

    bf16x8 Bm[32], Bs[16];
    if (!is6) {
#pragma unroll
        for (int kt = 0; kt < 10; ++kt) Bm[kt] = loadB(W5, kt * 32, colMain, l15, q8);
#pragma unroll
        for (int kt = 0; kt < 16; ++kt) Bm[10 + kt] = loadB(U5, kt * 32, colMain, l15, q8);
        if (wv < 2) {
#pragma unroll
            for (int kt = 0; kt < 10; ++kt) Bs[kt] = loadB(W5, kt * 32, colH, l15, q8);
        } else {
#pragma unroll
            for (int kt = 0; kt < 16; ++kt) Bs[kt] = loadB(U5, kt * 32, colH, l15, q8);
        }
    } else {
#pragma unroll
        for (int kt = 0; kt < 16; ++kt) Bm[kt] = loadB(W6, kt * 32, colMain, l15, q8);
#pragma unroll
        for (int kt = 0; kt < 16; ++kt) Bm[16 + kt] = loadB(U6, kt * 32, colMain, l15, q8);
        if (wv < 2) {
#pragma unroll
            for (int kt = 0; kt < 16; ++kt) Bs[kt] = loadB(W6, kt * 32, colH, l15, q8);
        } else {
#pragma unroll
            for (int kt = 0; kt < 16; ++kt) Bs[kt] = loadB(U6, kt * 32, colH, l15, q8);
        }
    }

    float wdv[8]; float bdv = 0.f;
    if (is6 && wv == 0) {
#pragma unroll
        for (int j = 0; j < 8; ++j) wdv[j] = Wd[lane * 8 + j];
        bdv = bdp[0];
    }

    const int grow = tid >> 4, cp = tid & 15;
    const int c2p = cp >> 3, ccb = (cp & 7) * 2;
    const int r_ = tid >> 4, cth = tid & 15;
    const int b_ = row0 + r_;

    // zin row is t-invariant: stage once to registers (16 f32/thread)
    float zreg[16];
#pragma unroll
    for (int k = 0; k < 16; ++k) zreg[k] = zin[(size_t)b_ * 256 + cth + 16 * k];

    // msk/x2 one-step-ahead prefetch registers (GRU5 only)
    float mk_r = 0.f, xr[4];
    if (!is6) {
        mk_r = msk[b_ * 512 + 0];
#pragma unroll
        for (int k = 0; k < 4; ++k)
            xr[k] = x2[(size_t)(b_ * 512 + 0) * 64 + cth + 16 * k];
    }

    float hold0 = 0.f, hold1 = 0.f;

    for (int t = 0; t < 514; ++t) {
        if (!is6) {
            if (t < 512) {
                // ---- stage masked x from prefetched regs ----
#pragma unroll
                for (int k = 0; k < 16; ++k)
                    stg[r_ * 840 + cth + 16 * k] = f2bf(zreg[k] * mk_r);
#pragma unroll
                for (int k = 0; k < 4; ++k)
                    stg[r_ * 840 + 256 + cth + 16 * k] = f2bf(xr[k] * mk_r);
                if (t + 1 < 512) {
                    mk_r = msk[b_ * 512 + t + 1];
#pragma unroll
                    for (int k = 0; k < 4; ++k)
                        xr[k] = x2[(size_t)(b_ * 512 + t + 1) * 64 + cth + 16 * k];
                }
                // ---- flag-gated read of h5[t-1] (tag t, slot t&7) ----
                {
                    flagwait(flg5 + (size_t)((t & 3) * 8 + rgp) * 32, (u32)t);
                    const u64* src = (const u64*)(h5w + (size_t)(t & 7) * 65536 +
                                                  (size_t)b_ * 512);
                    const u32 tgs = (u32)t << 16;
                    const u64 wself = ((u64)(tgs | (u32)f2bf(hold1)) << 32) |
                                      (u64)(tgs | (u32)f2bf(hold0));
                    u64 v[16];
                    readD(src, cth, (u32)t, slice, wself, v);
                    u16* dst = &stg[r_ * 840 + 320];
#pragma unroll
                    for (int k = 0; k < 16; ++k) {
                        u32 lo = (u32)v[k], hi = (u32)(v[k] >> 32);
                        *(u32*)&dst[(cth + 16 * k) * 2] = (lo & 0xffffu) | (hi << 16);
                    }
                }
                // ---- WAR guard, SLACK-7 (never binds): before writing tag
                //      t+1 (clobbers tag t-7 = h5[t-8], read by GRU6 at
                //      iter t-7), require GRU6 finished iter t-7 ----
                if (t >= 8 && wv == 0)
                    flagwait(flg6 + (size_t)(((t - 7) & 3) * 8 + rgp) * 32, (u32)(t - 7));
                __syncthreads();   // #1: staged + guard passed
                // ---- MFMA: x-part K=320 (W5), h-part K=512 (U5) ----
                f32x4 a0 = {biasM, biasM, biasM, biasM};
                f32x4 a1 = {biasS, biasS, biasS, biasS};
                if (wv < 2) {  // z + xh
#pragma unroll
                    for (int kt = 0; kt < 10; ++kt) {
                        bf16x8 a = ldsA(stg, 840, kt * 32, l15, q8);
                        a0 = MFMA(a, Bm[kt], a0);
                        a1 = MFMA(a, Bs[kt], a1);
                    }
#pragma unroll
                    for (int kt = 0; kt < 16; ++kt) {
                        bf16x8 a = ldsA(stg, 840, 320 + kt * 32, l15, q8);
                        a0 = MFMA(a, Bm[10 + kt], a0);
                    }
                } else {       // r + ih
#pragma unroll
                    for (int kt = 0; kt < 10; ++kt) {
                        bf16x8 a = ldsA(stg, 840, kt * 32, l15, q8);
                        a0 = MFMA(a, Bm[kt], a0);
                    }
#pragma unroll
                    for (int kt = 0; kt < 16; ++kt) {
                        bf16x8 a = ldsA(stg, 840, 320 + kt * 32, l15, q8);
                        a0 = MFMA(a, Bm[10 + kt], a0);
                        a1 = MFMA(a, Bs[kt], a1);
                    }
                }
                {
                    int uM = gMain * 2 + ct, uS = (wv < 2 ? 4 + ct : 6 + ct);
#pragma unroll
                    for (int i = 0; i < 4; ++i) {
                        int rr = (lane >> 4) * 4 + i;
                        exch[uM * 272 + rr * 17 + l15] = a0[i];
                        exch[uS * 272 + rr * 17 + l15] = a1[i];
                    }
                }
                __syncthreads();   // #2
                // ---- gate math; tagged store (tag t+1, slot (t+1)&7);
                //      then one advisory flag word ----
                {
                    int base0 = (0 + c2p) * 272 + grow * 17 + ccb;
                    int base1 = (2 + c2p) * 272 + grow * 17 + ccb;
                    int base2 = (4 + c2p) * 272 + grow * 17 + ccb;
                    int base3 = (6 + c2p) * 272 + grow * 17 + ccb;
                    float zv0 = exch[base0], zv1 = exch[base0 + 1];
                    float rv0 = exch[base1], rv1 = exch[base1 + 1];
                    float xh0 = exch[base2], xh1 = exch[base2 + 1];
                    float ih0 = exch[base3], ih1 = exch[base3 + 1];
                    float zg0 = sat01(0.2f * zv0 + 0.5f), zg1 = sat01(0.2f * zv1 + 0.5f);
                    float rt0 = sat01(0.2f * rv0 + 0.5f), rt1 = sat01(0.2f * rv1 + 0.5f);
                    float hh0 = ftanh(xh0 + rt0 * ih0), hh1 = ftanh(xh1 + rt1 * ih1);
                    float h0 = zg0 * hold0 + (1.f - zg0) * hh0;
                    float h1 = zg1 * hold1 + (1.f - zg1) * hh1;
                    hold0 = h0; hold1 = h1;
                    const u32 tg = (u32)(t + 1) << 16;
                    u64 w = ((u64)(tg | (u32)f2bf(h1)) << 32) | (u64)(tg | (u32)f2bf(h0));
                    u64* dst = (u64*)(h5w + (size_t)((t + 1) & 7) * 65536 +
                                      (size_t)row0 * 512);
                    __hip_atomic_store(&dst[(grow * 512 + sb + cp * 2) >> 1], w,
                                       __ATOMIC_RELAXED, AGENT);
                    if (tid == 0)
                        __hip_atomic_store(&flg5[(size_t)(((t + 1) & 3) * 8 + rgp) * 32 + slice],
                                           (u32)(t + 1), __ATOMIC_RELAXED, AGENT);
                }
            }
        } else {
            // ---- flag-gated reads: h5[t-1] (tag t, slot t&7, t<=512)
            //      and h6[t-2] (tag t-1, slot (t-1)&3) ----
            if (t >= 1) {
                const u32 exp2 = (u32)(t - 1);
                const u32 tgs = exp2 << 16;
                const u64 wself = ((u64)(tgs | (u32)f2bf(hold1)) << 32) |
                                  (u64)(tgs | (u32)f2bf(hold0));
                const u64* s2 = (const u64*)(h6w + (size_t)((t - 1) & 3) * 65536 +
                                             (size_t)b_ * 512);
                if (t <= 512) {
                    // joint flag wait (2 words/thread/round)
                    const u32* f5 = flg5 + (size_t)((t & 3) * 8 + rgp) * 32;
                    const u32* f6 = flg6 + (size_t)(((t - 1) & 3) * 8 + rgp) * 32;
                    const u32 exp1 = (u32)t;
                    while (true) {
                        u32 a = __hip_atomic_load(&f5[tid & 15], __ATOMIC_RELAXED, AGENT);
                        u32 b = __hip_atomic_load(&f6[tid & 15], __ATOMIC_RELAXED, AGENT);
                        if (__all((int)((a >= exp1) & (b >= exp2)))) break;
                        __builtin_amdgcn_s_sleep(1);
                    }
                    const u64* s1 = (const u64*)(h5w + (size_t)(t & 7) * 65536 +
                                                 (size_t)b_ * 512);
                    u64 v1[16], v2[16];
                    readD(s1, cth, exp1, -1, 0ull, v1);
                    readD(s2, cth, exp2, slice, wself, v2);
#pragma unroll
                    for (int k = 0; k < 16; ++k) {
                        int c = (cth + 16 * k) * 2;
                        u32 lo = (u32)v1[k], hi = (u32)(v1[k] >> 32);
                        *(u32*)&stg[r_ * 1032 + c] = (lo & 0xffffu) | (hi << 16);
                        lo = (u32)v2[k]; hi = (u32)(v2[k] >> 32);
                        *(u32*)&stg[r_ * 1032 + 512 + c] = (lo & 0xffffu) | (hi << 16);
                    }
                } else {  // t == 513: only h6[511] needed (for dec)
                    flagwait(flg6 + (size_t)(((t - 1) & 3) * 8 + rgp) * 32, exp2);
                    u64 v2[16];
                    readD(s2, cth, exp2, slice, wself, v2);
#pragma unroll
                    for (int k = 0; k < 16; ++k) {
                        int c = (cth + 16 * k) * 2;
                        u32 lo = (u32)v2[k], hi = (u32)(v2[k] >> 32);
                        *(u32*)&stg[r_ * 1032 + 512 + c] = (lo & 0xffffu) | (hi << 16);
                    }
                }
            }
            __syncthreads();   // #A: staged
            if (t >= 1 && t <= 512) {
                f32x4 a0 = {biasM, biasM, biasM, biasM};
                f32x4 a1 = {biasS, biasS, biasS, biasS};
                if (wv < 2) {  // z + xh
#pragma unroll
                    for (int kt = 0; kt < 16; ++kt) {
                        bf16x8 a = ldsA(stg, 1032, kt * 32, l15, q8);
                        a0 = MFMA(a, Bm[kt], a0);
                        a1 = MFMA(a, Bs[kt], a1);
                    }
#pragma unroll
                    for (int kt = 0; kt < 16; ++kt) {
                        bf16x8 a = ldsA(stg, 1032, 512 + kt * 32, l15, q8);
                        a0 = MFMA(a, Bm[16 + kt], a0);
                    }
                } else {       // r + ih
#pragma unroll
                    for (int kt = 0; kt < 16; ++kt) {
                        bf16x8 a = ldsA(stg, 1032, kt * 32, l15, q8);
                        a0 = MFMA(a, Bm[kt], a0);
                    }
#pragma unroll
                    for (int kt = 0; kt < 16; ++kt) {
                        bf16x8 a = ldsA(stg, 1032, 512 + kt * 32, l15, q8);
                        a0 = MFMA(a, Bm[16 + kt], a0);
                        a1 = MFMA(a, Bs[kt], a1);
                    }
                }
                {
                    int uM = gMain * 2 + ct, uS = (wv < 2 ? 4 + ct : 6 + ct);
#pragma unroll
                    for (int i = 0; i < 4; ++i) {
                        int rr = (lane >> 4) * 4 + i;
                        exch[uM * 272 + rr * 17 + l15] = a0[i];
                        exch[uS * 272 + rr * 17 + l15] = a1[i];
                    }
                }
                __syncthreads();   // #B
                {
                    int base0 = (0 + c2p) * 272 + grow * 17 + ccb;
                    int base1 = (2 + c2p) * 272 + grow * 17 + ccb;
                    int base2 = (4 + c2p) * 272 + grow * 17 + ccb;
                    int base3 = (6 + c2p) * 272 + grow * 17 + ccb;
                    float zv0 = exch[base0], zv1 = exch[base0 + 1];
                    float rv0 = exch[base1], rv1 = exch[base1 + 1];
                    float xh0 = exch[base2], xh1 = exch[base2 + 1];
                    float ih0 = exch[base3], ih1 = exch[base3 + 1];
                    float zg0 = sat01(0.2f * zv0 + 0.5f), zg1 = sat01(0.2f * zv1 + 0.5f);
                    float rt0 = sat01(0.2f * rv0 + 0.5f), rt1 = sat01(0.2f * rv1 + 0.5f);
                    float hh0 = ftanh(xh0 + rt0 * ih0), hh1 = ftanh(xh1 + rt1 * ih1);
                    float h0 = zg0 * hold0 + (1.f - zg0) * hh0;
                    float h1 = zg1 * hold1 + (1.f - zg1) * hh1;
                    hold0 = h0; hold1 = h1;
                    const u32 tg = (u32)t << 16;   // h6[t-1] stamped tag t
                    u64 w = ((u64)(tg | (u32)f2bf(h1)) << 32) | (u64)(tg | (u32)f2bf(h0));
                    u64* dst = (u64*)(h6w + (size_t)(t & 3) * 65536 +
                                      (size_t)row0 * 512);
                    __hip_atomic_store(&dst[(grow * 512 + sb + cp * 2) >> 1], w,
                                       __ATOMIC_RELAXED, AGENT);
                    if (tid == 0)
                        __hip_atomic_store(&flg6[(size_t)((t & 3) * 8 + rgp) * 32 + slice],
                                           (u32)t, __ATOMIC_RELAXED, AGENT);
                }
            }
            // dec[t-2] from LDS-staged h6[t-2]
            if (t >= 2 && wv == 0) {
                const u16* hrow = &stg[slice * 1032 + 512 + lane * 8];
                bf16x8 hv = *(const bf16x8*)hrow;
                float s = 0.f;
#pragma unroll
                for (int j = 0; j < 8; ++j) s += bf2f((u16)hv[j]) * wdv[j];
#pragma unroll
                for (int off = 32; off >= 1; off >>= 1) s += __shfl_down(s, off);
                if (lane == 0) {
                    int bb = row0 + slice, tt = t - 2;
                    out[bb * 512 + tt] = ftanh(s + bdv) * dmsk[bb * 512 + tt];
                }
            }
            __syncthreads();   // protect stg reuse across iterations
        }
    }
}

extern "C" void kernel_launch(void* const* d_in, const int* in_sizes, int n_in,
                              void* d_out, int out_size, void* d_ws, size_t ws_size,
                              hipStream_t stream) {
    const float* zin = (const float*)d_in[0];
    const float* x2  = (const float*)d_in[1];
    const float* msk = (const float*)d_in[2];
    const float* dmk = (const float*)d_in[3];
    const float* W5  = (const float*)d_in[4];
    const float* U5  = (const float*)d_in[5];
    const float* bi5 = (const float*)d_in[6];
    const float* br5 = (const float*)d_in[7];
    const float* W6  = (const float*)d_in[8];
    const float* U6  = (const float*)d_in[9];
    const float* bi6 = (const float*)d_in[10];
    const float* br6 = (const float*)d_in[11];
    const float* Wd  = (const float*)d_in[12];
    const float* bd  = (const float*)d_in[13];
    float* out = (float*)d_out;

    // ws (u32): h5w[8][128][512] (2MB) | h6w[4][128][512] (1MB) |
    //           flg5[4][8][32] (4KB) | flg6[4][8][32] (4KB)
    u32* h5w = (u32*)d_ws;
    u32* h6w = h5w + 524288;
    u32* flg5 = h6w + 262144;
    u32* flg6 = flg5 + 1024;

    zero_ws_kernel<<<dim3(3080), dim3(256), 0, stream>>>((u32*)d_ws);

    gru_fused<<<dim3(256), dim3(256), 0, stream>>>(
        zin, x2, msk, dmk, W5, U5, bi5, br5, W6, U6, bi6, br6,
        Wd, bd, out, h5w, h6w, flg5, flg6);
}

// Round 9
// 2175.018 us; speedup vs baseline: 1.6649x; 1.6649x over previous
//
#include <hip/hip_runtime.h>
#include <hip/hip_bf16.h>

typedef unsigned short u16;
typedef unsigned int u32;
typedef unsigned long long u64;
typedef __attribute__((ext_vector_type(8))) short bf16x8;   // 8 bf16 (4 VGPRs)
typedef __attribute__((ext_vector_type(4))) float f32x4;

#define MFMA(a,b,c) __builtin_amdgcn_mfma_f32_16x16x32_bf16((a),(b),(c),0,0,0)
#define AGENT __HIP_MEMORY_SCOPE_AGENT
#define WGSC  __HIP_MEMORY_SCOPE_WORKGROUP

// v10 = v4 EXACT protocol (the only measured winner: 2038us) + two
// individually-safe deltas. Protocol summary (all v4-verbatim):
//  - XCC_ID role claiming + deterministic consensus; fallback wg-static
//  - dual publish: plain store (same-XCD L2 dirty line -> consumer's first
//    L1-cold plain round catches it early) + agent store (IC, correctness)
//  - polls ride ON THE DATA (tagged words), 1:1 plain/agent round cadence,
//    sleep(1) after agent rounds; agent rounds guarantee progress
//  - 4-deep rings (slot = tag&3); GRU5 WAR guard at slack-3 via h6 tags
//  - 40KB LDS pad -> 1 wg/CU
// Deltas vs v4:
//  (1) msk/x2 prefetched one step ahead into registers (their HBM/L2
//      latency was serial before the poll in v4)
//  (2) GRU6 polls h5[t-1] alone (v4 cadence), then h6[t-2] separately
//      (same cadence + self-word substitution) instead of jointly
//      re-reading both every round -> half the per-round volume.
// Lessons encoded from refuted rounds: no buffer_inv (v3/v5), no single
// store (v6), no swap (v7), no beacons (v8), no flag indirection (v9) —
// detection must be on the data; both publish copies are load-bearing.
//
// B=128, T=512, LAT=256, F2=64, H=512, DIN=320, 3H=1536
// roles: rgp 0..7 (16 rows), rid 0..31: rid<16 GRU5 slice, else GRU6 slice.
// iter t (514): GRU5 -> h5[t] (t<512, tag t+1, slot (t+1)&3);
//   GRU6 -> h6[t-1] (1<=t<=512, tag t, slot t&3); dec[t-2] (t>=2).
// Tags: every h word u32 = (step_tag<<16)|bf16, self-validating per word.

__device__ __forceinline__ u16 f2bf(float f) {
    u32 u = __float_as_uint(f);
    u32 r = (u + 0x7fffu + ((u >> 16) & 1u)) >> 16;
    return (u16)r;
}
__device__ __forceinline__ float bf2f(u16 v) { return __uint_as_float(((u32)v) << 16); }
__device__ __forceinline__ float sat01(float x) { return fminf(1.f, fmaxf(0.f, x)); }
__device__ __forceinline__ float ftanh(float x) {
    x = fminf(10.f, fmaxf(-10.f, x));
    float e = __expf(2.f * x);
    return (e - 1.f) / (e + 1.f);
}

// v4's dual-cadence tagged 16-word poll, with optional self-word register
// substitution (own slice never gates on own store's round-trip).
__device__ __forceinline__ void poll16(const u64* __restrict__ src, int cth, u32 exp,
                                       bool lcl, int self_k, u64 self_w, u64* v) {
    int round = 0;
    while (true) {
        const bool ag = (!lcl) || ((round & 1) == 1);
        if (ag) {
#pragma unroll
            for (int k = 0; k < 16; ++k) {
                u64 x = __hip_atomic_load(&src[cth + 16 * k], __ATOMIC_RELAXED, AGENT);
                v[k] = (k == self_k) ? self_w : x;
            }
        } else {
#pragma unroll
            for (int k = 0; k < 16; ++k) {
                u64 x = __hip_atomic_load(&src[cth + 16 * k], __ATOMIC_RELAXED, WGSC);
                v[k] = (k == self_k) ? self_w : x;
            }
        }
        bool ok = true;
#pragma unroll
        for (int k = 0; k < 16; ++k) {
            u32 lo = (u32)v[k], hi = (u32)(v[k] >> 32);
            if (((lo >> 16) != exp) | ((hi >> 16) != exp)) ok = false;
        }
        if (ok) break;
        if (ag) __builtin_amdgcn_s_sleep(1);
        ++round;
    }
}

__device__ __forceinline__ bf16x8 loadB(const float* __restrict__ M, int k0, int colbase,
                                        int l15, int q8) {
    const float* p = M + (size_t)(k0 + q8) * 1536 + colbase + l15;
    bf16x8 r;
#pragma unroll
    for (int j = 0; j < 8; ++j) r[j] = (short)f2bf(p[(size_t)j * 1536]);
    return r;
}

__device__ __forceinline__ bf16x8 ldsA(const u16* s, int stride, int colbase, int l15, int q8) {
    return *(const bf16x8*)(s + l15 * stride + colbase + q8);
}

__global__ void zero_ws_kernel(u32* ws) {
    int i = blockIdx.x * 256 + threadIdx.x;
    if (i < 524296) ws[i] = 0u;  // h5w[4][128][512] + h6w[4][128][512] + claim[8]
}

__global__ void __launch_bounds__(256, 1)
gru_fused(const float* __restrict__ zin, const float* __restrict__ x2,
          const float* __restrict__ msk, const float* __restrict__ dmsk,
          const float* __restrict__ W5, const float* __restrict__ U5,
          const float* __restrict__ bi5, const float* __restrict__ br5,
          const float* __restrict__ W6, const float* __restrict__ U6,
          const float* __restrict__ bi6, const float* __restrict__ br6,
          const float* __restrict__ Wd, const float* __restrict__ bdp,
          float* __restrict__ out, u32* __restrict__ h5w,
          u32* __restrict__ h6w, u32* __restrict__ claim)
{
    const int wg = blockIdx.x;
    const int tid = threadIdx.x;
    const int wv = tid >> 6, lane = tid & 63;
    const int l15 = lane & 15, q8 = (lane >> 4) << 3;

    __shared__ u16 stg[16 * 1032];
    __shared__ float exch[8 * 16 * 17];
    __shared__ u32 lds_pad[10240];   // 40KB: total LDS > 80KB -> 1 wg/CU forced
    __shared__ u32 s_tk, s_good;

    ((volatile u32*)lds_pad)[tid] = 0u;   // keep pad alive

    // ---- XCD role claiming + deterministic consensus (v4, proven) ----
    const int xcd = (int)(__builtin_amdgcn_s_getreg((31u << 11) | 20u) & 7u); // HW_REG_XCC_ID
    if (tid == 0) {
        u32 tk = __hip_atomic_fetch_add(&claim[xcd], 1u, __ATOMIC_RELAXED, AGENT);
        s_tk = tk;
        u32 c[8]; u32 tot;
        do {
            tot = 0;
#pragma unroll
            for (int g = 0; g < 8; ++g) {
                c[g] = __hip_atomic_load(&claim[g], __ATOMIC_RELAXED, AGENT);
                tot += c[g];
            }
            if (tot < 256u) __builtin_amdgcn_s_sleep(8);
        } while (tot < 256u);
        u32 good = 1u;
#pragma unroll
        for (int g = 0; g < 8; ++g) if (c[g] != 32u) good = 0u;
        s_good = good;
    }
    __syncthreads();
    const bool lcl = (s_good != 0u);
    const int rgp = lcl ? xcd : (wg & 7);
    const int rid = lcl ? (int)s_tk : (wg >> 3);
    const bool is6 = rid >= 16;
    const int slice = is6 ? (rid - 16) : rid;
    const int row0 = rgp << 4;
    const int sb = slice << 5;

    const int ct = wv & 1;
    const int gMain = (wv < 2) ? 0 : 1;
    const int colMain = gMain * 512 + sb + ct * 16;
    const int colH = 1024 + sb + ct * 16;

    const float* bi = is6 ? bi6 : bi5;
    const float* br = is6 ? br6 : br5;
    const float biasM = bi[colMain + l15] + br[colMain + l15];
    const float biasS = (wv < 2) ? bi[colH + l15] : br[colH + l15];

    bf16x8 Bm[32], Bs[16];
    if (!is6) {
#pragma unroll
        for (int kt = 0; kt < 10; ++kt) Bm[kt] = loadB(W5, kt * 32, colMain, l15, q8);
#pragma unroll
        for (int kt = 0; kt < 16; ++kt) Bm[10 + kt] = loadB(U5, kt * 32, colMain, l15, q8);
        if (wv < 2) {
#pragma unroll
            for (int kt = 0; kt < 10; ++kt) Bs[kt] = loadB(W5, kt * 32, colH, l15, q8);
        } else {
#pragma unroll
            for (int kt = 0; kt < 16; ++kt) Bs[kt] = loadB(U5, kt * 32, colH, l15, q8);
        }
    } else {
#pragma unroll
        for (int kt = 0; kt < 16; ++kt) Bm[kt] = loadB(W6, kt * 32, colMain, l15, q8);
#pragma unroll
        for (int kt = 0; kt < 16; ++kt) Bm[16 + kt] = loadB(U6, kt * 32, colMain, l15, q8);
        if (wv < 2) {
#pragma unroll
            for (int kt = 0; kt < 16; ++kt) Bs[kt] = loadB(W6, kt * 32, colH, l15, q8);
        } else {
#pragma unroll
            for (int kt = 0; kt < 16; ++kt) Bs[kt] = loadB(U6, kt * 32, colH, l15, q8);
        }
    }

    float wdv[8]; float bdv = 0.f;
    if (is6 && wv == 0) {
#pragma unroll
        for (int j = 0; j < 8; ++j) wdv[j] = Wd[lane * 8 + j];
        bdv = bdp[0];
    }

    const int grow = tid >> 4, cp = tid & 15;
    const int c2p = cp >> 3, ccb = (cp & 7) * 2;
    const int r_ = tid >> 4, cth = tid & 15;
    const int b_ = row0 + r_;

    // zin row is t-invariant: stage once to registers (16 f32/thread)
    float zreg[16];
#pragma unroll
    for (int k = 0; k < 16; ++k) zreg[k] = zin[(size_t)b_ * 256 + cth + 16 * k];

    // msk/x2 one-step-ahead prefetch registers (GRU5 only)  [delta 1]
    float mk_r = 0.f, xr[4];
    if (!is6) {
        mk_r = msk[b_ * 512 + 0];
#pragma unroll
        for (int k = 0; k < 4; ++k)
            xr[k] = x2[(size_t)(b_ * 512 + 0) * 64 + cth + 16 * k];
    }

    float hold0 = 0.f, hold1 = 0.f;

    for (int t = 0; t < 514; ++t) {
        if (!is6) {
            if (t < 512) {
                // ---- stage masked x from prefetched regs ----
#pragma unroll
                for (int k = 0; k < 16; ++k)
                    stg[r_ * 840 + cth + 16 * k] = f2bf(zreg[k] * mk_r);
#pragma unroll
                for (int k = 0; k < 4; ++k)
                    stg[r_ * 840 + 256 + cth + 16 * k] = f2bf(xr[k] * mk_r);
                // prefetch t+1 (hides under poll)
                if (t + 1 < 512) {
                    mk_r = msk[b_ * 512 + t + 1];
#pragma unroll
                    for (int k = 0; k < 4; ++k)
                        xr[k] = x2[(size_t)(b_ * 512 + t + 1) * 64 + cth + 16 * k];
                }
                // ---- poll h5[t-1]: tag t, slot t&3 (v4 cadence + self) ----
                {
                    const u64* src = (const u64*)(h5w + (size_t)(t & 3) * 65536 +
                                                  (size_t)b_ * 512);
                    const u32 tgs = (u32)t << 16;
                    const u64 wself = ((u64)(tgs | (u32)f2bf(hold1)) << 32) |
                                      (u64)(tgs | (u32)f2bf(hold0));
                    u64 v[16];
                    poll16(src, cth, (u32)t, lcl, slice, wself, v);
                    u16* dst = &stg[r_ * 840 + 320];
#pragma unroll
                    for (int k = 0; k < 16; ++k) {
                        u32 lo = (u32)v[k], hi = (u32)(v[k] >> 32);
                        *(u32*)&dst[(cth + 16 * k) * 2] = (lo & 0xffffu) | (hi << 16);
                    }
                }
                // ---- WAR guard, slack 3 (v4 verbatim) ----
                if (t >= 4 && wv == 0) {
                    const u32 exp6 = (u32)(t - 3);
                    const u32* q = h6w + (size_t)((t - 3) & 3) * 65536 +
                                   (size_t)row0 * 512 + (lane & 15) * 32;
                    int round = 0;
                    while (true) {
                        const bool ag = (!lcl) || ((round & 1) == 1);
                        u32 w = ag ? __hip_atomic_load(q, __ATOMIC_RELAXED, AGENT)
                                   : __hip_atomic_load(q, __ATOMIC_RELAXED, WGSC);
                        if (__all((int)((w >> 16) >= exp6))) break;
                        if (ag) __builtin_amdgcn_s_sleep(1);
                        ++round;
                    }
                }
                __syncthreads();
                // ---- MFMA: x-part K=320 (W5), h-part K=512 (U5) ----
                f32x4 a0 = {biasM, biasM, biasM, biasM};
                f32x4 a1 = {biasS, biasS, biasS, biasS};
                if (wv < 2) {  // z + xh
#pragma unroll
                    for (int kt = 0; kt < 10; ++kt) {
                        bf16x8 a = ldsA(stg, 840, kt * 32, l15, q8);
                        a0 = MFMA(a, Bm[kt], a0);
                        a1 = MFMA(a, Bs[kt], a1);
                    }
#pragma unroll
                    for (int kt = 0; kt < 16; ++kt) {
                        bf16x8 a = ldsA(stg, 840, 320 + kt * 32, l15, q8);
                        a0 = MFMA(a, Bm[10 + kt], a0);
                    }
                } else {       // r + ih
#pragma unroll
                    for (int kt = 0; kt < 10; ++kt) {
                        bf16x8 a = ldsA(stg, 840, kt * 32, l15, q8);
                        a0 = MFMA(a, Bm[kt], a0);
                    }
#pragma unroll
                    for (int kt = 0; kt < 16; ++kt) {
                        bf16x8 a = ldsA(stg, 840, 320 + kt * 32, l15, q8);
                        a0 = MFMA(a, Bm[10 + kt], a0);
                        a1 = MFMA(a, Bs[kt], a1);
                    }
                }
                {
                    int uM = gMain * 2 + ct, uS = (wv < 2 ? 4 + ct : 6 + ct);
#pragma unroll
                    for (int i = 0; i < 4; ++i) {
                        int rr = (lane >> 4) * 4 + i;
                        exch[uM * 272 + rr * 17 + l15] = a0[i];
                        exch[uS * 272 + rr * 17 + l15] = a1[i];
                    }
                }
                __syncthreads();
                // ---- gate math; tagged u64 dual publish (v4) ----
                {
                    int base0 = (0 + c2p) * 272 + grow * 17 + ccb;
                    int base1 = (2 + c2p) * 272 + grow * 17 + ccb;
                    int base2 = (4 + c2p) * 272 + grow * 17 + ccb;
                    int base3 = (6 + c2p) * 272 + grow * 17 + ccb;
                    float zv0 = exch[base0], zv1 = exch[base0 + 1];
                    float rv0 = exch[base1], rv1 = exch[base1 + 1];
                    float xh0 = exch[base2], xh1 = exch[base2 + 1];
                    float ih0 = exch[base3], ih1 = exch[base3 + 1];
                    float zg0 = sat01(0.2f * zv0 + 0.5f), zg1 = sat01(0.2f * zv1 + 0.5f);
                    float rt0 = sat01(0.2f * rv0 + 0.5f), rt1 = sat01(0.2f * rv1 + 0.5f);
                    float hh0 = ftanh(xh0 + rt0 * ih0), hh1 = ftanh(xh1 + rt1 * ih1);
                    float h0 = zg0 * hold0 + (1.f - zg0) * hh0;
                    float h1 = zg1 * hold1 + (1.f - zg1) * hh1;
                    hold0 = h0; hold1 = h1;
                    const u32 tg = (u32)(t + 1) << 16;
                    u64 w = ((u64)(tg | (u32)f2bf(h1)) << 32) | (u64)(tg | (u32)f2bf(h0));
                    u64* dst = (u64*)(h5w + (size_t)((t + 1) & 3) * 65536 +
                                      (size_t)row0 * 512);
                    u64* p = &dst[(grow * 512 + sb + cp * 2) >> 1];
                    if (lcl) __hip_atomic_store(p, w, __ATOMIC_RELAXED, WGSC);  // local L2
                    __hip_atomic_store(p, w, __ATOMIC_RELAXED, AGENT);          // IC copy
                }
            }
        } else {
            // ---- split polls [delta 2]: h5[t-1] first (fresh), then
            //      h6[t-2] (old, usually one round) ----
            if (t >= 1) {
                if (t <= 512) {
                    const u64* s1 = (const u64*)(h5w + (size_t)(t & 3) * 65536 +
                                                 (size_t)b_ * 512);
                    u64 v1[16];
                    poll16(s1, cth, (u32)t, lcl, -1, 0ull, v1);
#pragma unroll
                    for (int k = 0; k < 16; ++k) {
                        int c = (cth + 16 * k) * 2;
                        u32 lo = (u32)v1[k], hi = (u32)(v1[k] >> 32);
                        *(u32*)&stg[r_ * 1032 + c] = (lo & 0xffffu) | (hi << 16);
                    }
                }
                {
                    const u64* s2 = (const u64*)(h6w + (size_t)((t - 1) & 3) * 65536 +
                                                 (size_t)b_ * 512);
                    const u32 exp2 = (u32)(t - 1);
                    const u32 tgs = exp2 << 16;
                    const u64 wself = ((u64)(tgs | (u32)f2bf(hold1)) << 32) |
                                      (u64)(tgs | (u32)f2bf(hold0));
                    u64 v2[16];
                    poll16(s2, cth, exp2, lcl, slice, wself, v2);
#pragma unroll
                    for (int k = 0; k < 16; ++k) {
                        int c = (cth + 16 * k) * 2;
                        u32 lo = (u32)v2[k], hi = (u32)(v2[k] >> 32);
                        *(u32*)&stg[r_ * 1032 + 512 + c] = (lo & 0xffffu) | (hi << 16);
                    }
                }
            }
            __syncthreads();
            if (t >= 1 && t <= 512) {
                f32x4 a0 = {biasM, biasM, biasM, biasM};
                f32x4 a1 = {biasS, biasS, biasS, biasS};
                if (wv < 2) {  // z + xh
#pragma unroll
                    for (int kt = 0; kt < 16; ++kt) {
                        bf16x8 a = ldsA(stg, 1032, kt * 32, l15, q8);
                        a0 = MFMA(a, Bm[kt], a0);
                        a1 = MFMA(a, Bs[kt], a1);
                    }
#pragma unroll
                    for (int kt = 0; kt < 16; ++kt) {
                        bf16x8 a = ldsA(stg, 1032, 512 + kt * 32, l15, q8);
                        a0 = MFMA(a, Bm[16 + kt], a0);
                    }
                } else {       // r + ih
#pragma unroll
                    for (int kt = 0; kt < 16; ++kt) {
                        bf16x8 a = ldsA(stg, 1032, kt * 32, l15, q8);
                        a0 = MFMA(a, Bm[kt], a0);
                    }
#pragma unroll
                    for (int kt = 0; kt < 16; ++kt) {
                        bf16x8 a = ldsA(stg, 1032, 512 + kt * 32, l15, q8);
                        a0 = MFMA(a, Bm[16 + kt], a0);
                        a1 = MFMA(a, Bs[kt], a1);
                    }
                }
                {
                    int uM = gMain * 2 + ct, uS = (wv < 2 ? 4 + ct : 6 + ct);
#pragma unroll
                    for (int i = 0; i < 4; ++i) {
                        int rr = (lane >> 4) * 4 + i;
                        exch[uM * 272 + rr * 17 + l15] = a0[i];
                        exch[uS * 272 + rr * 17 + l15] = a1[i];
                    }
                }
                __syncthreads();
                {
                    int base0 = (0 + c2p) * 272 + grow * 17 + ccb;
                    int base1 = (2 + c2p) * 272 + grow * 17 + ccb;
                    int base2 = (4 + c2p) * 272 + grow * 17 + ccb;
                    int base3 = (6 + c2p) * 272 + grow * 17 + ccb;
                    float zv0 = exch[base0], zv1 = exch[base0 + 1];
                    float rv0 = exch[base1], rv1 = exch[base1 + 1];
                    float xh0 = exch[base2], xh1 = exch[base2 + 1];
                    float ih0 = exch[base3], ih1 = exch[base3 + 1];
                    float zg0 = sat01(0.2f * zv0 + 0.5f), zg1 = sat01(0.2f * zv1 + 0.5f);
                    float rt0 = sat01(0.2f * rv0 + 0.5f), rt1 = sat01(0.2f * rv1 + 0.5f);
                    float hh0 = ftanh(xh0 + rt0 * ih0), hh1 = ftanh(xh1 + rt1 * ih1);
                    float h0 = zg0 * hold0 + (1.f - zg0) * hh0;
                    float h1 = zg1 * hold1 + (1.f - zg1) * hh1;
                    hold0 = h0; hold1 = h1;
                    const u32 tg = (u32)t << 16;   // h6[t-1] stamped (t-1)+1 = t
                    u64 w = ((u64)(tg | (u32)f2bf(h1)) << 32) | (u64)(tg | (u32)f2bf(h0));
                    u64* dst = (u64*)(h6w + (size_t)(t & 3) * 65536 +
                                      (size_t)row0 * 512);
                    u64* p = &dst[(grow * 512 + sb + cp * 2) >> 1];
                    if (lcl) __hip_atomic_store(p, w, __ATOMIC_RELAXED, WGSC);  // local L2
                    __hip_atomic_store(p, w, __ATOMIC_RELAXED, AGENT);          // IC copy
                }
            }
            // dec[t-2] from LDS-staged h6[t-2]
            if (t >= 2 && wv == 0) {
                const u16* hrow = &stg[slice * 1032 + 512 + lane * 8];
                bf16x8 hv = *(const bf16x8*)hrow;
                float s = 0.f;
#pragma unroll
                for (int j = 0; j < 8; ++j) s += bf2f((u16)hv[j]) * wdv[j];
#pragma unroll
                for (int off = 32; off >= 1; off >>= 1) s += __shfl_down(s, off);
                if (lane == 0) {
                    int bb = row0 + slice, tt = t - 2;
                    out[bb * 512 + tt] = ftanh(s + bdv) * dmsk[bb * 512 + tt];
                }
            }
            __syncthreads();   // protect stg reuse across iterations
        }
    }
}

extern "C" void kernel_launch(void* const* d_in, const int* in_sizes, int n_in,
                              void* d_out, int out_size, void* d_ws, size_t ws_size,
                              hipStream_t stream) {
    const float* zin = (const float*)d_in[0];
    const float* x2  = (const float*)d_in[1];
    const float* msk = (const float*)d_in[2];
    const float* dmk = (const float*)d_in[3];
    const float* W5  = (const float*)d_in[4];
    const float* U5  = (const float*)d_in[5];
    const float* bi5 = (const float*)d_in[6];
    const float* br5 = (const float*)d_in[7];
    const float* W6  = (const float*)d_in[8];
    const float* U6  = (const float*)d_in[9];
    const float* bi6 = (const float*)d_in[10];
    const float* br6 = (const float*)d_in[11];
    const float* Wd  = (const float*)d_in[12];
    const float* bd  = (const float*)d_in[13];
    float* out = (float*)d_out;

    // ws (u32 units): h5w [4][128][512] | h6w [4][128][512] | claim[8]
    u32* h5w = (u32*)d_ws;                 // 1 MB
    u32* h6w = h5w + 262144;               // 1 MB
    u32* claim = h6w + 262144;             // 32 B

    zero_ws_kernel<<<dim3(2049), dim3(256), 0, stream>>>((u32*)d_ws);

    gru_fused<<<dim3(256), dim3(256), 0, stream>>>(
        zin, x2, msk, dmk, W5, U5, bi5, br5, W6, U6, bi6, br6,
        Wd, bd, out, h5w, h6w, claim);
}